// Round 1
// baseline (201.162 us; speedup 1.0000x reference)
//
#include <hip/hip_runtime.h>
#include <hip/hip_bf16.h>
#include <stdint.h>

typedef __bf16 bf16;
typedef __bf16 bf16x4 __attribute__((ext_vector_type(4)));
typedef __bf16 bf16x8 __attribute__((ext_vector_type(8)));
typedef float f32x4 __attribute__((ext_vector_type(4)));

__device__ __forceinline__ f32x4 mfma16(bf16x8 a, bf16x8 b, f32x4 c) {
    return __builtin_amdgcn_mfma_f32_16x16x32_bf16(a, b, c, 0, 0, 0);
}

__device__ __forceinline__ void gload_lds16(const void* g, void* l) {
    __builtin_amdgcn_global_load_lds((__attribute__((address_space(1))) void*)g,
                                     (__attribute__((address_space(3))) void*)l,
                                     16, 0, 0);
}

// ---------------- cast fp32 -> bf16 (vectorized x4) ----------------
__global__ void k_cast_bf16(const float* __restrict__ in, bf16* __restrict__ out, int n4) {
    int i = blockIdx.x * blockDim.x + threadIdx.x;
    int stride = gridDim.x * blockDim.x;
    for (; i < n4; i += stride) {
        float4 v = reinterpret_cast<const float4*>(in)[i];
        bf16x4 o = { (bf16)v.x, (bf16)v.y, (bf16)v.z, (bf16)v.w };
        reinterpret_cast<bf16x4*>(out)[i] = o;
    }
}

// ---------------- GEMM: C[M,N] = A[M,K] * W[N,K]^T + bias ----------------
// 128x128 tile, BK=32, 256 threads = 4 waves (2x2), each wave 64x64 = 4x4 frags.
template<bool BF16_OUT>
__global__ __launch_bounds__(256) void k_gemm_bt(
        const bf16* __restrict__ A, const bf16* __restrict__ W,
        const float* __restrict__ bias, void* __restrict__ Cout,
        int M, int N, int K) {
    __shared__ bf16 As[128 * 32];
    __shared__ bf16 Ws[128 * 32];
    const int tid = threadIdx.x;
    const int l = tid & 63, w = tid >> 6;
    const int lr = l & 15, lq = l >> 4;
    const int wm = w >> 1, wn = w & 1;
    const int bm = blockIdx.y * 128, bn = blockIdx.x * 128;

    f32x4 acc[4][4] = {};

    for (int k0 = 0; k0 < K; k0 += 32) {
        __syncthreads();
        #pragma unroll
        for (int i = 0; i < 2; ++i) {
            int c = tid + i * 256;              // 0..511
            int row = c >> 2, c8 = (c & 3) * 8; // 128 rows x 32 cols, 16B chunks
            gload_lds16(A + (size_t)(bm + row) * K + k0 + c8, As + c * 8);
            gload_lds16(W + (size_t)(bn + row) * K + k0 + c8, Ws + c * 8);
        }
        __syncthreads();
        bf16x8 af[4], wf[4];
        #pragma unroll
        for (int f = 0; f < 4; ++f) {
            af[f] = *reinterpret_cast<const bf16x8*>(As + (wm * 64 + f * 16 + lr) * 32 + lq * 8);
            wf[f] = *reinterpret_cast<const bf16x8*>(Ws + (wn * 64 + f * 16 + lr) * 32 + lq * 8);
        }
        #pragma unroll
        for (int fm = 0; fm < 4; ++fm)
            #pragma unroll
            for (int fn = 0; fn < 4; ++fn)
                acc[fm][fn] = mfma16(af[fm], wf[fn], acc[fm][fn]);
    }

    // epilogue: C/D layout col = lane&15, row = (lane>>4)*4 + r (m89-verified)
    #pragma unroll
    for (int fm = 0; fm < 4; ++fm) {
        #pragma unroll
        for (int fn = 0; fn < 4; ++fn) {
            int row = bm + wm * 64 + fm * 16 + lq * 4;
            int col = bn + wn * 64 + fn * 16 + lr;
            float bv = bias[col];
            #pragma unroll
            for (int r = 0; r < 4; ++r) {
                float v = acc[fm][fn][r] + bv;
                if (BF16_OUT)
                    ((bf16*)Cout)[(size_t)(row + r) * N + col] = (bf16)v;
                else
                    ((float*)Cout)[(size_t)(row + r) * N + col] = v;
            }
        }
    }
}

// ---------------- causal flash attention ----------------
// qkv: [4096][2304] bf16 (q|k|v each 768, head h at h*64). att: [4096][768] bf16.
// Block = one (b, h, 64-row q-block); 4 waves x 16 q-rows; KV tile = 64.
#define ATT_SCALE 0.70710678118654752f  // 1/sqrt(B=2), faithful to reference

__global__ __launch_bounds__(256) void k_flash_attn(
        const bf16* __restrict__ qkv, bf16* __restrict__ att) {
    __shared__ bf16 Vt[64][72];       // [d][kv], kv XOR-swizzled by ((d>>3)&7)<<3
    __shared__ bf16 Pl[4][16][72];    // per-wave P tile [q][kv]

    const int tid = threadIdx.x;
    const int l = tid & 63, w = tid >> 6;
    const int lr = l & 15, lq = l >> 4;

    const int bid = blockIdx.x;
    const int qb = bid & 31;
    const int h  = (bid >> 5) % 12;
    const int b  = bid / (32 * 12);

    const bf16* Qp = qkv + (size_t)b * 2048 * 2304 + h * 64;
    const bf16* Kp = Qp + 768;
    const bf16* Vp = Qp + 1536;

    const int qr0 = qb * 64 + w * 16;

    bf16x8 qf[2];
    #pragma unroll
    for (int ks = 0; ks < 2; ++ks)
        qf[ks] = *reinterpret_cast<const bf16x8*>(
            Qp + (size_t)(qr0 + lr) * 2304 + ks * 32 + lq * 8);

    f32x4 o[4] = {};
    float mrow[4] = {-INFINITY, -INFINITY, -INFINITY, -INFINITY};
    float lrow[4] = {0.f, 0.f, 0.f, 0.f};

    const int ntiles = qb + 1;  // causal: only kv tiles with kv0 <= q-block end
    for (int jt = 0; jt < ntiles; ++jt) {
        const int kv0 = jt * 64;
        __syncthreads();  // protect Vt reuse across iterations
        // stage V transposed into LDS
        #pragma unroll
        for (int i = 0; i < 2; ++i) {
            int c = tid + i * 256;             // 0..511
            int kv = c >> 3, d0 = (c & 7) * 8;
            bf16x8 vv = *reinterpret_cast<const bf16x8*>(
                Vp + (size_t)(kv0 + kv) * 2304 + d0);
            #pragma unroll
            for (int j = 0; j < 8; ++j) {
                int d = d0 + j;
                Vt[d][kv ^ (((d >> 3) & 7) << 3)] = vv[j];
            }
        }
        __syncthreads();

        const bool diag = (jt == qb);
        f32x4 p[4];
        #pragma unroll
        for (int t = 0; t < 4; ++t) {
            f32x4 s = {0.f, 0.f, 0.f, 0.f};
            #pragma unroll
            for (int ks = 0; ks < 2; ++ks) {
                bf16x8 kf = *reinterpret_cast<const bf16x8*>(
                    Kp + (size_t)(kv0 + t * 16 + lr) * 2304 + ks * 32 + lq * 8);
                s = mfma16(qf[ks], kf, s);  // S[q=(lq*4+r)][k=lr]
            }
            #pragma unroll
            for (int r = 0; r < 4; ++r) {
                float v = s[r] * ATT_SCALE;
                if (diag && (kv0 + t * 16 + lr > qr0 + lq * 4 + r)) v = -INFINITY;
                p[t][r] = v;
            }
        }
        // online softmax: rows live across 16-lane groups
        float alpha[4];
        #pragma unroll
        for (int r = 0; r < 4; ++r) {
            float mx = fmaxf(fmaxf(p[0][r], p[1][r]), fmaxf(p[2][r], p[3][r]));
            #pragma unroll
            for (int off = 1; off < 16; off <<= 1)
                mx = fmaxf(mx, __shfl_xor(mx, off));
            float mn = fmaxf(mrow[r], mx);
            alpha[r] = __expf(mrow[r] - mn);   // first iter: exp(-inf - finite) = 0
            mrow[r] = mn;
            float sum = 0.f;
            #pragma unroll
            for (int t = 0; t < 4; ++t) {
                float e = __expf(p[t][r] - mn);
                p[t][r] = e;
                sum += e;
            }
            #pragma unroll
            for (int off = 1; off < 16; off <<= 1)
                sum += __shfl_xor(sum, off);
            lrow[r] = lrow[r] * alpha[r] + sum;
        }
        #pragma unroll
        for (int db = 0; db < 4; ++db)
            #pragma unroll
            for (int r = 0; r < 4; ++r)
                o[db][r] *= alpha[r];
        // P -> LDS (C/D layout to A-fragment layout fix)
        #pragma unroll
        for (int t = 0; t < 4; ++t)
            #pragma unroll
            for (int r = 0; r < 4; ++r)
                Pl[w][lq * 4 + r][t * 16 + lr] = (bf16)p[t][r];
        // PV: o[16q x 64d] += P[16q x 64kv] * V[64kv x 64d]
        #pragma unroll
        for (int ks = 0; ks < 2; ++ks) {
            bf16x8 pa = *reinterpret_cast<const bf16x8*>(&Pl[w][lr][ks * 32 + lq * 8]);
            #pragma unroll
            for (int db = 0; db < 4; ++db) {
                int row = db * 16 + lr;
                bf16x8 vf = *reinterpret_cast<const bf16x8*>(
                    &Vt[row][(ks * 32 + lq * 8) ^ (((row >> 3) & 7) << 3)]);
                o[db] = mfma16(pa, vf, o[db]);
            }
        }
    }
    // normalize + store
    #pragma unroll
    for (int db = 0; db < 4; ++db)
        #pragma unroll
        for (int r = 0; r < 4; ++r) {
            float v = o[db][r] / lrow[r];
            att[(size_t)(b * 2048 + qr0 + lq * 4 + r) * 768 + h * 64 + db * 16 + lr] = (bf16)v;
        }
}

// ---------------- launch ----------------
extern "C" void kernel_launch(void* const* d_in, const int* in_sizes, int n_in,
                              void* d_out, int out_size, void* d_ws, size_t ws_size,
                              hipStream_t stream) {
    const float* x      = (const float*)d_in[0];
    const float* w_attn = (const float*)d_in[1];
    const float* b_attn = (const float*)d_in[2];
    const float* w_proj = (const float*)d_in[3];
    const float* b_proj = (const float*)d_in[4];

    char* ws = (char*)d_ws;
    bf16* xb  = (bf16*)(ws + 0);          // 4096x768   = 6291456 B
    bf16* wab = (bf16*)(ws + 6291456);    // 2304x768   = 3538944 B
    bf16* wpb = (bf16*)(ws + 9830400);    //  768x768   = 1179648 B
    bf16* qkv = (bf16*)(ws + 11010048);   // 4096x2304  = 18874368 B
    bf16* att = (bf16*)(ws + 29884416);   // 4096x768   = 6291456 B  (end ~36.2 MB)

    k_cast_bf16<<<1024, 256, 0, stream>>>(x, xb, 3145728 / 4);
    k_cast_bf16<<<512, 256, 0, stream>>>(w_attn, wab, 1769472 / 4);
    k_cast_bf16<<<256, 256, 0, stream>>>(w_proj, wpb, 589824 / 4);

    dim3 g1(2304 / 128, 4096 / 128);
    k_gemm_bt<true><<<g1, 256, 0, stream>>>(xb, wab, b_attn, qkv, 4096, 2304, 768);

    k_flash_attn<<<768, 256, 0, stream>>>(qkv, att);

    dim3 g2(768 / 128, 4096 / 128);
    k_gemm_bt<false><<<g2, 256, 0, stream>>>(att, wpb, b_proj, d_out, 4096, 768, 768);
}

// Round 2
// 136.344 us; speedup vs baseline: 1.4754x; 1.4754x over previous
//
#include <hip/hip_runtime.h>
#include <hip/hip_bf16.h>
#include <stdint.h>

typedef __bf16 bf16;
typedef __bf16 bf16x4 __attribute__((ext_vector_type(4)));
typedef __bf16 bf16x8 __attribute__((ext_vector_type(8)));
typedef float f32x4 __attribute__((ext_vector_type(4)));

__device__ __forceinline__ f32x4 mfma16(bf16x8 a, bf16x8 b, f32x4 c) {
    return __builtin_amdgcn_mfma_f32_16x16x32_bf16(a, b, c, 0, 0, 0);
}

__device__ __forceinline__ void gload_lds16(const void* g, void* l) {
    __builtin_amdgcn_global_load_lds((__attribute__((address_space(1))) void*)g,
                                     (__attribute__((address_space(3))) void*)l,
                                     16, 0, 0);
}

// ---------------- cast fp32 -> bf16 (vectorized x4) ----------------
__global__ void k_cast_bf16(const float* __restrict__ in, bf16* __restrict__ out, int n4) {
    int i = blockIdx.x * blockDim.x + threadIdx.x;
    int stride = gridDim.x * blockDim.x;
    for (; i < n4; i += stride) {
        float4 v = reinterpret_cast<const float4*>(in)[i];
        bf16x4 o = { (bf16)v.x, (bf16)v.y, (bf16)v.z, (bf16)v.w };
        reinterpret_cast<bf16x4*>(out)[i] = o;
    }
}

// ---------------- GEMM: C[M,N] = A[M,K] * W[N,K]^T + bias ----------------
template<bool BF16_OUT>
__global__ __launch_bounds__(256) void k_gemm_bt(
        const bf16* __restrict__ A, const bf16* __restrict__ W,
        const float* __restrict__ bias, void* __restrict__ Cout,
        int M, int N, int K) {
    __shared__ bf16 As[128 * 32];
    __shared__ bf16 Ws[128 * 32];
    const int tid = threadIdx.x;
    const int l = tid & 63, w = tid >> 6;
    const int lr = l & 15, lq = l >> 4;
    const int wm = w >> 1, wn = w & 1;
    const int bm = blockIdx.y * 128, bn = blockIdx.x * 128;

    f32x4 acc[4][4] = {};

    for (int k0 = 0; k0 < K; k0 += 32) {
        __syncthreads();
        #pragma unroll
        for (int i = 0; i < 2; ++i) {
            int c = tid + i * 256;
            int row = c >> 2, c8 = (c & 3) * 8;
            gload_lds16(A + (size_t)(bm + row) * K + k0 + c8, As + c * 8);
            gload_lds16(W + (size_t)(bn + row) * K + k0 + c8, Ws + c * 8);
        }
        __syncthreads();
        bf16x8 af[4], wf[4];
        #pragma unroll
        for (int f = 0; f < 4; ++f) {
            af[f] = *reinterpret_cast<const bf16x8*>(As + (wm * 64 + f * 16 + lr) * 32 + lq * 8);
            wf[f] = *reinterpret_cast<const bf16x8*>(Ws + (wn * 64 + f * 16 + lr) * 32 + lq * 8);
        }
        #pragma unroll
        for (int fm = 0; fm < 4; ++fm)
            #pragma unroll
            for (int fn = 0; fn < 4; ++fn)
                acc[fm][fn] = mfma16(af[fm], wf[fn], acc[fm][fn]);
    }

    #pragma unroll
    for (int fm = 0; fm < 4; ++fm) {
        #pragma unroll
        for (int fn = 0; fn < 4; ++fn) {
            int row = bm + wm * 64 + fm * 16 + lq * 4;
            int col = bn + wn * 64 + fn * 16 + lr;
            float bv = bias[col];
            #pragma unroll
            for (int r = 0; r < 4; ++r) {
                float v = acc[fm][fn][r] + bv;
                if (BF16_OUT)
                    ((bf16*)Cout)[(size_t)(row + r) * N + col] = (bf16)v;
                else
                    ((float*)Cout)[(size_t)(row + r) * N + col] = v;
            }
        }
    }
}

// ---------------- causal flash attention (no-max softmax, 2-phase pipeline) ----------------
// qkv: [4096][2304] bf16 (q|k|v each 768, head h at h*64). att: [4096][768] bf16.
// scale 1/sqrt(B=2) faithful to reference; folded: exp2(s * 0.70710678 * log2(e))
#define CLOG2E 1.02014439f

__global__ __launch_bounds__(256) void k_flash_attn(
        const bf16* __restrict__ qkv, bf16* __restrict__ att) {
    __shared__ bf16 Ks[2][4096];      // [kv][d] XOR-swizzled chunks: dest chunk j holds src chunk j^(row&7)
    __shared__ bf16 Vt[2][64][72];    // [d][kv], kv XOR-swizzled by ((d>>3)&7)<<3
    __shared__ bf16 Pl[4][16][72];    // per-wave P tile [q][kv]

    const int tid = threadIdx.x;
    const int l = tid & 63, w = tid >> 6;
    const int lr = l & 15, lq = l >> 4;

    const int bid = blockIdx.x;
    const int qb = bid & 31;
    const int h  = (bid >> 5) % 12;
    const int b  = bid / 384;

    const bf16* Qp = qkv + (size_t)b * 2048 * 2304 + h * 64;
    const bf16* Kp = Qp + 768;
    const bf16* Vp = Qp + 1536;

    const int qr0 = qb * 64 + w * 16;

    bf16x8 qf[2];
    #pragma unroll
    for (int ks = 0; ks < 2; ++ks)
        qf[ks] = *reinterpret_cast<const bf16x8*>(
            Qp + (size_t)(qr0 + lr) * 2304 + ks * 32 + lq * 8);

    f32x4 o[4] = {};
    float lsum[4] = {0.f, 0.f, 0.f, 0.f};

    // staging coordinates (chunk c = tid + i*256; row=c>>3, j=c&7)
    auto stageK = [&](int buf, int kv0) {
        #pragma unroll
        for (int i = 0; i < 2; ++i) {
            int c = tid + i * 256;
            int row = c >> 3, j = c & 7;
            gload_lds16(Kp + (size_t)(kv0 + row) * 2304 + ((j ^ (row & 7)) * 8),
                        &Ks[buf][c * 8]);
        }
    };
    bf16x8 vv0, vv1;
    auto loadV = [&](int kv0) {
        vv0 = *reinterpret_cast<const bf16x8*>(
            Vp + (size_t)(kv0 + (tid >> 3)) * 2304 + (tid & 7) * 8);
        vv1 = *reinterpret_cast<const bf16x8*>(
            Vp + (size_t)(kv0 + 32 + (tid >> 3)) * 2304 + (tid & 7) * 8);
    };
    auto writeV = [&](int buf) {
        int kv = tid >> 3, d0 = (tid & 7) * 8;
        int sw = (tid & 7) << 3;  // ((d>>3)&7)<<3, d>>3 == tid&7 for all 8 j
        #pragma unroll
        for (int j = 0; j < 8; ++j) {
            int d = d0 + j;
            Vt[buf][d][kv ^ sw]        = vv0[j];
            Vt[buf][d][(kv + 32) ^ sw] = vv1[j];
        }
    };

    const int ntiles = qb + 1;

    // prologue: tile 0
    stageK(0, 0);
    loadV(0);
    asm volatile("s_waitcnt vmcnt(0)" ::: "memory");
    writeV(0);
    __syncthreads();

    for (int jt = 0; jt < ntiles; ++jt) {
        const int cur = jt & 1;
        const int kv0 = jt * 64;
        const bool hn = (jt + 1 < ntiles);
        if (hn) {                       // prefetch next tile while computing this one
            stageK(cur ^ 1, kv0 + 64);
            loadV(kv0 + 64);
        }

        const bool diag = (jt == qb);
        const int rsw = lr & 7;
        float p[4][4];
        #pragma unroll
        for (int t = 0; t < 4; ++t) {
            f32x4 s = {0.f, 0.f, 0.f, 0.f};
            #pragma unroll
            for (int ks = 0; ks < 2; ++ks) {
                bf16x8 kf = *reinterpret_cast<const bf16x8*>(
                    &Ks[cur][(t * 16 + lr) * 64 + (((ks * 4 + lq) ^ rsw) * 8)]);
                s = mfma16(qf[ks], kf, s);   // S[q=(lq*4+r)][k=lr]
            }
            #pragma unroll
            for (int r = 0; r < 4; ++r) {
                float e = exp2f(s[r] * CLOG2E);
                if (diag && (t * 16 + lr > w * 16 + lq * 4 + r)) e = 0.f;
                p[t][r] = e;
            }
        }
        #pragma unroll
        for (int r = 0; r < 4; ++r)
            lsum[r] += (p[0][r] + p[1][r]) + (p[2][r] + p[3][r]);

        // P -> LDS (C/D layout -> A-fragment layout fix)
        #pragma unroll
        for (int t = 0; t < 4; ++t)
            #pragma unroll
            for (int r = 0; r < 4; ++r)
                Pl[w][lq * 4 + r][t * 16 + lr] = (bf16)p[t][r];

        // PV: o[16q x 64d] += P[16q x 64kv] * V[64kv x 64d]
        #pragma unroll
        for (int ks = 0; ks < 2; ++ks) {
            bf16x8 pa = *reinterpret_cast<const bf16x8*>(&Pl[w][lr][ks * 32 + lq * 8]);
            #pragma unroll
            for (int db = 0; db < 4; ++db) {
                int row = db * 16 + lr;
                bf16x8 vf = *reinterpret_cast<const bf16x8*>(
                    &Vt[cur][row][(ks * 32 + lq * 8) ^ (((row >> 3) & 7) << 3)]);
                o[db] = mfma16(pa, vf, o[db]);
            }
        }

        if (hn) writeV(cur ^ 1);   // vv arrived (compiler waits); Vt[cur^1] free since last barrier
        __syncthreads();           // drains gload_lds (vmcnt) + makes Vt visible
    }

    // single end-of-kernel row-sum reduction across the 16 lanes holding each row
    #pragma unroll
    for (int r = 0; r < 4; ++r) {
        #pragma unroll
        for (int off = 1; off < 16; off <<= 1)
            lsum[r] += __shfl_xor(lsum[r], off);
    }
    #pragma unroll
    for (int db = 0; db < 4; ++db)
        #pragma unroll
        for (int r = 0; r < 4; ++r) {
            float v = o[db][r] / lsum[r];
            att[(size_t)(b * 2048 + qr0 + lq * 4 + r) * 768 + h * 64 + db * 16 + lr] = (bf16)v;
        }
}

// ---------------- launch ----------------
extern "C" void kernel_launch(void* const* d_in, const int* in_sizes, int n_in,
                              void* d_out, int out_size, void* d_ws, size_t ws_size,
                              hipStream_t stream) {
    const float* x      = (const float*)d_in[0];
    const float* w_attn = (const float*)d_in[1];
    const float* b_attn = (const float*)d_in[2];
    const float* w_proj = (const float*)d_in[3];
    const float* b_proj = (const float*)d_in[4];

    char* ws = (char*)d_ws;
    bf16* xb  = (bf16*)(ws + 0);          // 4096x768   = 6291456 B
    bf16* wab = (bf16*)(ws + 6291456);    // 2304x768   = 3538944 B
    bf16* wpb = (bf16*)(ws + 9830400);    //  768x768   = 1179648 B
    bf16* qkv = (bf16*)(ws + 11010048);   // 4096x2304  = 18874368 B
    bf16* att = (bf16*)(ws + 29884416);   // 4096x768   = 6291456 B

    k_cast_bf16<<<1024, 256, 0, stream>>>(x, xb, 3145728 / 4);
    k_cast_bf16<<<512, 256, 0, stream>>>(w_attn, wab, 1769472 / 4);
    k_cast_bf16<<<256, 256, 0, stream>>>(w_proj, wpb, 589824 / 4);

    dim3 g1(2304 / 128, 4096 / 128);
    k_gemm_bt<true><<<g1, 256, 0, stream>>>(xb, wab, b_attn, qkv, 4096, 2304, 768);

    k_flash_attn<<<768, 256, 0, stream>>>(qkv, att);

    dim3 g2(768 / 128, 4096 / 128);
    k_gemm_bt<false><<<g2, 256, 0, stream>>>(att, wpb, b_proj, d_out, 4096, 768, 768);
}

// Round 3
// 107.074 us; speedup vs baseline: 1.8787x; 1.2734x over previous
//
#include <hip/hip_runtime.h>
#include <hip/hip_bf16.h>
#include <stdint.h>

typedef __bf16 bf16;
typedef __bf16 bf16x4 __attribute__((ext_vector_type(4)));
typedef __bf16 bf16x8 __attribute__((ext_vector_type(8)));
typedef float f32x4 __attribute__((ext_vector_type(4)));

__device__ __forceinline__ f32x4 mfma16(bf16x8 a, bf16x8 b, f32x4 c) {
    return __builtin_amdgcn_mfma_f32_16x16x32_bf16(a, b, c, 0, 0, 0);
}

__device__ __forceinline__ void gload_lds16(const void* g, void* l) {
    __builtin_amdgcn_global_load_lds((__attribute__((address_space(1))) void*)g,
                                     (__attribute__((address_space(3))) void*)l,
                                     16, 0, 0);
}

// ---------------- fused cast fp32 -> bf16 for all three inputs ----------------
__global__ void k_cast3(const float* __restrict__ x, const float* __restrict__ wa,
                        const float* __restrict__ wp, bf16* __restrict__ xb,
                        bf16* __restrict__ wab, bf16* __restrict__ wpb) {
    const int N1 = 786432, N2 = 442368, N3 = 147456;  // float4 chunks
    int i = blockIdx.x * blockDim.x + threadIdx.x;
    int stride = gridDim.x * blockDim.x;
    for (; i < N1 + N2 + N3; i += stride) {
        const float* src; bf16* dst; int j = i;
        if (j < N1)           { src = x;  dst = xb; }
        else if (j < N1 + N2) { src = wa; dst = wab; j -= N1; }
        else                  { src = wp; dst = wpb; j -= N1 + N2; }
        float4 v = reinterpret_cast<const float4*>(src)[j];
        bf16x4 o = { (bf16)v.x, (bf16)v.y, (bf16)v.z, (bf16)v.w };
        reinterpret_cast<bf16x4*>(dst)[j] = o;
    }
}

// ---------------- GEMM: C[M,N] = A[M,K] * W[N,K]^T + bias ----------------
template<bool BF16_OUT>
__global__ __launch_bounds__(256) void k_gemm_bt(
        const bf16* __restrict__ A, const bf16* __restrict__ W,
        const float* __restrict__ bias, void* __restrict__ Cout,
        int M, int N, int K) {
    __shared__ bf16 As[128 * 32];
    __shared__ bf16 Ws[128 * 32];
    const int tid = threadIdx.x;
    const int l = tid & 63, w = tid >> 6;
    const int lr = l & 15, lq = l >> 4;
    const int wm = w >> 1, wn = w & 1;
    const int bm = blockIdx.y * 128, bn = blockIdx.x * 128;

    f32x4 acc[4][4] = {};

    for (int k0 = 0; k0 < K; k0 += 32) {
        __syncthreads();
        #pragma unroll
        for (int i = 0; i < 2; ++i) {
            int c = tid + i * 256;
            int row = c >> 2, c8 = (c & 3) * 8;
            gload_lds16(A + (size_t)(bm + row) * K + k0 + c8, As + c * 8);
            gload_lds16(W + (size_t)(bn + row) * K + k0 + c8, Ws + c * 8);
        }
        __syncthreads();
        bf16x8 af[4], wf[4];
        #pragma unroll
        for (int f = 0; f < 4; ++f) {
            af[f] = *reinterpret_cast<const bf16x8*>(As + (wm * 64 + f * 16 + lr) * 32 + lq * 8);
            wf[f] = *reinterpret_cast<const bf16x8*>(Ws + (wn * 64 + f * 16 + lr) * 32 + lq * 8);
        }
        #pragma unroll
        for (int fm = 0; fm < 4; ++fm)
            #pragma unroll
            for (int fn = 0; fn < 4; ++fn)
                acc[fm][fn] = mfma16(af[fm], wf[fn], acc[fm][fn]);
    }

    #pragma unroll
    for (int fm = 0; fm < 4; ++fm) {
        #pragma unroll
        for (int fn = 0; fn < 4; ++fn) {
            int row = bm + wm * 64 + fm * 16 + lq * 4;
            int col = bn + wn * 64 + fn * 16 + lr;
            float bv = bias[col];
            #pragma unroll
            for (int r = 0; r < 4; ++r) {
                float v = acc[fm][fn][r] + bv;
                if (BF16_OUT)
                    ((bf16*)Cout)[(size_t)(row + r) * N + col] = (bf16)v;
                else
                    ((float*)Cout)[(size_t)(row + r) * N + col] = v;
            }
        }
    }
}

// ---------------- causal flash attention ----------------
// Swapped QK^T (mfma(K,Q)) + T12 in-register P redistribution; balanced qb map.
#define CLOG2E 1.02014439f   // (1/sqrt(2)) * log2(e)

__global__ __launch_bounds__(256, 4) void k_flash_attn(
        const bf16* __restrict__ qkv, bf16* __restrict__ att) {
    __shared__ bf16 Ks[2][4096];      // [kv][d], chunk j of row holds src chunk j^(row&7)
    __shared__ bf16 Vt[2][64][72];    // [d][kv], kv XOR-swizzled by ((d>>3)&7)<<3

    const int tid = threadIdx.x;
    const int l = tid & 63, w = tid >> 6;
    const int lr = l & 15, lq = l >> 4;

    // balanced qb mapping: CU c (stride-256 aliasing) gets qb triple summing to 46/47
    const int bid = blockIdx.x;
    const int s = bid >> 8, i = (bid >> 3) & 31, t7 = bid & 7;
    int qb;
    if (s == 0)      qb = i;
    else if (s == 2) qb = (i + 16) & 31;
    else             qb = (i < 8) ? (31 - 2 * i) : (i < 16) ? (30 - 2 * i)
                       : (i < 24) ? (62 - 2 * i) : (63 - 2 * i);
    const int hb = s * 8 + t7;
    const int h = hb % 12, b = hb / 12;

    const bf16* Qp = qkv + (size_t)b * 2048 * 2304 + h * 64;
    const bf16* Kp = Qp + 768;
    const bf16* Vp = Qp + 1536;

    const int qr0 = qb * 64 + w * 16;

    bf16x8 qf[2];
    #pragma unroll
    for (int ks = 0; ks < 2; ++ks)
        qf[ks] = *reinterpret_cast<const bf16x8*>(
            Qp + (size_t)(qr0 + lr) * 2304 + ks * 32 + lq * 8);

    f32x4 o[4] = {};
    float lsum = 0.f;

    auto stageK = [&](int buf, int kv0) {
        #pragma unroll
        for (int ii = 0; ii < 2; ++ii) {
            int c = tid + ii * 256;
            int row = c >> 3, j = c & 7;
            gload_lds16(Kp + (size_t)(kv0 + row) * 2304 + ((j ^ (row & 7)) * 8),
                        &Ks[buf][c * 8]);
        }
    };
    bf16x8 vv0, vv1;
    auto loadV = [&](int kv0) {
        vv0 = *reinterpret_cast<const bf16x8*>(
            Vp + (size_t)(kv0 + (tid >> 3)) * 2304 + (tid & 7) * 8);
        vv1 = *reinterpret_cast<const bf16x8*>(
            Vp + (size_t)(kv0 + 32 + (tid >> 3)) * 2304 + (tid & 7) * 8);
    };
    auto writeV = [&](int buf) {
        int kv = tid >> 3, d0 = (tid & 7) * 8;
        int sw = (tid & 7) << 3;
        #pragma unroll
        for (int j = 0; j < 8; ++j) {
            int d = d0 + j;
            Vt[buf][d][kv ^ sw]        = vv0[j];
            Vt[buf][d][(kv + 32) ^ sw] = vv1[j];
        }
    };

    const int ntiles = qb + 1;

    stageK(0, 0);
    loadV(0);
    asm volatile("s_waitcnt vmcnt(0)" ::: "memory");
    writeV(0);
    __syncthreads();

    for (int jt = 0; jt < ntiles; ++jt) {
        const int cur = jt & 1;
        const int kv0 = jt * 64;
        const bool hn = (jt + 1 < ntiles);
        if (hn) {
            stageK(cur ^ 1, kv0 + 64);
            loadV(kv0 + 64);
        }

        const bool diag = (jt == qb);
        const int rsw = lr & 7;
        float p[4][4];
        #pragma unroll
        for (int t = 0; t < 4; ++t) {
            f32x4 sacc = {0.f, 0.f, 0.f, 0.f};
            #pragma unroll
            for (int ks = 0; ks < 2; ++ks) {
                bf16x8 kf = *reinterpret_cast<const bf16x8*>(
                    &Ks[cur][(t * 16 + lr) * 64 + (((ks * 4 + lq) ^ rsw) * 8)]);
                sacc = mfma16(kf, qf[ks], sacc);   // S[k=t*16+lq*4+r][q=lr]
            }
            #pragma unroll
            for (int r = 0; r < 4; ++r) {
                float e = exp2f(sacc[r] * CLOG2E);
                if (diag && (t * 16 + lq * 4 + r > w * 16 + lr)) e = 0.f;
                p[t][r] = e;
                lsum += e;
            }
        }

        // T12: pack P to bf16 and redistribute across lq groups via permlane swaps
        unsigned P0[4], P1[4];
        #pragma unroll
        for (int t = 0; t < 4; ++t) {
            asm("v_cvt_pk_bf16_f32 %0, %1, %2" : "=v"(P0[t]) : "v"(p[t][0]), "v"(p[t][1]));
            asm("v_cvt_pk_bf16_f32 %0, %1, %2" : "=v"(P1[t]) : "v"(p[t][2]), "v"(p[t][3]));
        }
        #pragma unroll
        for (int ks = 0; ks < 2; ++ks) {
            unsigned a0 = P0[2 * ks], b0 = P0[2 * ks + 1];
            asm volatile("v_permlane32_swap_b32 %0, %1" : "+v"(a0), "+v"(b0));
            asm volatile("v_permlane16_swap_b32 %0, %1" : "+v"(a0), "+v"(b0));
            unsigned a1 = P1[2 * ks], b1 = P1[2 * ks + 1];
            asm volatile("v_permlane32_swap_b32 %0, %1" : "+v"(a1), "+v"(b1));
            asm volatile("v_permlane16_swap_b32 %0, %1" : "+v"(a1), "+v"(b1));
            union { unsigned u[4]; bf16x8 v8; } pk_;
            pk_.u[0] = a0; pk_.u[1] = a1; pk_.u[2] = b0; pk_.u[3] = b1;
            bf16x8 pa = pk_.v8;   // P[q=lr][kv = ks*32 + lq*8 + e]
            #pragma unroll
            for (int db = 0; db < 4; ++db) {
                int row = db * 16 + lr;
                bf16x8 vf = *reinterpret_cast<const bf16x8*>(
                    &Vt[cur][row][(ks * 32 + lq * 8) ^ (((row >> 3) & 7) << 3)]);
                o[db] = mfma16(pa, vf, o[db]);
            }
        }

        if (hn) writeV(cur ^ 1);
        __syncthreads();
    }

    // full row-sums: reduce across the 4 lq groups, then gather per output row
    lsum += __shfl_xor(lsum, 16);
    lsum += __shfl_xor(lsum, 32);
    float inv[4];
    #pragma unroll
    for (int r = 0; r < 4; ++r)
        inv[r] = 1.0f / __shfl(lsum, lq * 4 + r);

    #pragma unroll
    for (int db = 0; db < 4; ++db)
        #pragma unroll
        for (int r = 0; r < 4; ++r) {
            float v = o[db][r] * inv[r];
            att[(size_t)(b * 2048 + qr0 + lq * 4 + r) * 768 + h * 64 + db * 16 + lr] = (bf16)v;
        }
}

// ---------------- launch ----------------
extern "C" void kernel_launch(void* const* d_in, const int* in_sizes, int n_in,
                              void* d_out, int out_size, void* d_ws, size_t ws_size,
                              hipStream_t stream) {
    const float* x      = (const float*)d_in[0];
    const float* w_attn = (const float*)d_in[1];
    const float* b_attn = (const float*)d_in[2];
    const float* w_proj = (const float*)d_in[3];
    const float* b_proj = (const float*)d_in[4];

    char* ws = (char*)d_ws;
    bf16* xb  = (bf16*)(ws + 0);          // 4096x768   = 6291456 B
    bf16* wab = (bf16*)(ws + 6291456);    // 2304x768   = 3538944 B
    bf16* wpb = (bf16*)(ws + 9830400);    //  768x768   = 1179648 B
    bf16* qkv = (bf16*)(ws + 11010048);   // 4096x2304  = 18874368 B
    bf16* att = (bf16*)(ws + 29884416);   // 4096x768   = 6291456 B

    k_cast3<<<2048, 256, 0, stream>>>(x, w_attn, w_proj, xb, wab, wpb);

    dim3 g1(2304 / 128, 4096 / 128);
    k_gemm_bt<true><<<g1, 256, 0, stream>>>(xb, wab, b_attn, qkv, 4096, 2304, 768);

    k_flash_attn<<<768, 256, 0, stream>>>(qkv, att);

    dim3 g2(768 / 128, 4096 / 128);
    k_gemm_bt<false><<<g2, 256, 0, stream>>>(att, wpb, b_proj, d_out, 4096, 768, 768);
}

// Round 4
// 105.661 us; speedup vs baseline: 1.9038x; 1.0134x over previous
//
#include <hip/hip_runtime.h>
#include <hip/hip_bf16.h>
#include <stdint.h>

typedef __bf16 bf16;
typedef __bf16 bf16x4 __attribute__((ext_vector_type(4)));
typedef __bf16 bf16x8 __attribute__((ext_vector_type(8)));
typedef float f32x4 __attribute__((ext_vector_type(4)));

__device__ __forceinline__ f32x4 mfma16(bf16x8 a, bf16x8 b, f32x4 c) {
    return __builtin_amdgcn_mfma_f32_16x16x32_bf16(a, b, c, 0, 0, 0);
}

__device__ __forceinline__ void gload_lds16(const void* g, void* l) {
    __builtin_amdgcn_global_load_lds((__attribute__((address_space(1))) void*)g,
                                     (__attribute__((address_space(3))) void*)l,
                                     16, 0, 0);
}

// ---------------- fused cast fp32 -> bf16 for all three inputs ----------------
__global__ void k_cast3(const float* __restrict__ x, const float* __restrict__ wa,
                        const float* __restrict__ wp, bf16* __restrict__ xb,
                        bf16* __restrict__ wab, bf16* __restrict__ wpb) {
    const int N1 = 786432, N2 = 442368, N3 = 147456;  // float4 chunks
    int i = blockIdx.x * blockDim.x + threadIdx.x;
    int stride = gridDim.x * blockDim.x;
    for (; i < N1 + N2 + N3; i += stride) {
        const float* src; bf16* dst; int j = i;
        if (j < N1)           { src = x;  dst = xb; }
        else if (j < N1 + N2) { src = wa; dst = wab; j -= N1; }
        else                  { src = wp; dst = wpb; j -= N1 + N2; }
        float4 v = reinterpret_cast<const float4*>(src)[j];
        bf16x4 o = { (bf16)v.x, (bf16)v.y, (bf16)v.z, (bf16)v.w };
        reinterpret_cast<bf16x4*>(dst)[j] = o;
    }
}

// ---------------- GEMM: C[M,N] = A[M,K] * W[N,K]^T + bias ----------------
template<bool BF16_OUT>
__global__ __launch_bounds__(256) void k_gemm_bt(
        const bf16* __restrict__ A, const bf16* __restrict__ W,
        const float* __restrict__ bias, void* __restrict__ Cout,
        int M, int N, int K) {
    __shared__ bf16 As[128 * 32];
    __shared__ bf16 Ws[128 * 32];
    const int tid = threadIdx.x;
    const int l = tid & 63, w = tid >> 6;
    const int lr = l & 15, lq = l >> 4;
    const int wm = w >> 1, wn = w & 1;
    const int bm = blockIdx.y * 128, bn = blockIdx.x * 128;

    f32x4 acc[4][4] = {};

    for (int k0 = 0; k0 < K; k0 += 32) {
        __syncthreads();
        #pragma unroll
        for (int i = 0; i < 2; ++i) {
            int c = tid + i * 256;
            int row = c >> 2, c8 = (c & 3) * 8;
            gload_lds16(A + (size_t)(bm + row) * K + k0 + c8, As + c * 8);
            gload_lds16(W + (size_t)(bn + row) * K + k0 + c8, Ws + c * 8);
        }
        __syncthreads();
        bf16x8 af[4], wf[4];
        #pragma unroll
        for (int f = 0; f < 4; ++f) {
            af[f] = *reinterpret_cast<const bf16x8*>(As + (wm * 64 + f * 16 + lr) * 32 + lq * 8);
            wf[f] = *reinterpret_cast<const bf16x8*>(Ws + (wn * 64 + f * 16 + lr) * 32 + lq * 8);
        }
        #pragma unroll
        for (int fm = 0; fm < 4; ++fm)
            #pragma unroll
            for (int fn = 0; fn < 4; ++fn)
                acc[fm][fn] = mfma16(af[fm], wf[fn], acc[fm][fn]);
    }

    #pragma unroll
    for (int fm = 0; fm < 4; ++fm) {
        #pragma unroll
        for (int fn = 0; fn < 4; ++fn) {
            int row = bm + wm * 64 + fm * 16 + lq * 4;
            int col = bn + wn * 64 + fn * 16 + lr;
            float bv = bias[col];
            #pragma unroll
            for (int r = 0; r < 4; ++r) {
                float v = acc[fm][fn][r] + bv;
                if (BF16_OUT)
                    ((bf16*)Cout)[(size_t)(row + r) * N + col] = (bf16)v;
                else
                    ((float*)Cout)[(size_t)(row + r) * N + col] = v;
            }
        }
    }
}

// ---------------- causal flash attention ----------------
// Swapped QK^T + T12 in-register P redistribution; balanced qb map;
// triple-buffered K staged 2 tiles ahead + raw barriers (no vmcnt drain).
#define CLOG2E 1.02014439f   // (1/sqrt(2)) * log2(e)

__global__ __launch_bounds__(256, 3) void k_flash_attn(
        const bf16* __restrict__ qkv, bf16* __restrict__ att) {
    __shared__ bf16 Ks[3][4096];      // [kv][d], chunk j of row holds src chunk j^(row&7)
    __shared__ bf16 Vt[2][64][72];    // [d][kv], kv XOR-swizzled by ((d>>3)&7)<<3

    const int tid = threadIdx.x;
    const int l = tid & 63, w = tid >> 6;
    const int lr = l & 15, lq = l >> 4;

    // balanced qb mapping: CU c (stride-256 aliasing) gets qb triple summing to 46/47
    const int bid = blockIdx.x;
    const int s = bid >> 8, i = (bid >> 3) & 31, t7 = bid & 7;
    int qb;
    if (s == 0)      qb = i;
    else if (s == 2) qb = (i + 16) & 31;
    else             qb = (i < 8) ? (31 - 2 * i) : (i < 16) ? (30 - 2 * i)
                       : (i < 24) ? (62 - 2 * i) : (63 - 2 * i);
    const int hb = s * 8 + t7;
    const int h = hb % 12, b = hb / 12;

    const bf16* Qp = qkv + (size_t)b * 2048 * 2304 + h * 64;
    const bf16* Kp = Qp + 768;
    const bf16* Vp = Qp + 1536;

    const int qr0 = qb * 64 + w * 16;

    bf16x8 qf[2];
    #pragma unroll
    for (int ks = 0; ks < 2; ++ks)
        qf[ks] = *reinterpret_cast<const bf16x8*>(
            Qp + (size_t)(qr0 + lr) * 2304 + ks * 32 + lq * 8);

    f32x4 o[4] = {};
    float lsum = 0.f;

    auto stageK = [&](int buf, int kv0) {
        #pragma unroll
        for (int ii = 0; ii < 2; ++ii) {
            int c = tid + ii * 256;
            int row = c >> 3, j = c & 7;
            gload_lds16(Kp + (size_t)(kv0 + row) * 2304 + ((j ^ (row & 7)) * 8),
                        &Ks[buf][c * 8]);
        }
    };
    bf16x8 vv0, vv1;
    auto loadV = [&](int kv0) {
        vv0 = *reinterpret_cast<const bf16x8*>(
            Vp + (size_t)(kv0 + (tid >> 3)) * 2304 + (tid & 7) * 8);
        vv1 = *reinterpret_cast<const bf16x8*>(
            Vp + (size_t)(kv0 + 32 + (tid >> 3)) * 2304 + (tid & 7) * 8);
    };
    auto writeV = [&](int buf) {
        int kv = tid >> 3, d0 = (tid & 7) * 8;
        int sw = (tid & 7) << 3;
        #pragma unroll
        for (int j = 0; j < 8; ++j) {
            int d = d0 + j;
            Vt[buf][d][kv ^ sw]        = vv0[j];
            Vt[buf][d][(kv + 32) ^ sw] = vv1[j];
        }
    };

    const int ntiles = qb + 1;

    // prologue: K for tiles 0,1 staged; V0 in LDS; full drain once.
    stageK(0, 0);
    if (ntiles > 1) stageK(1, 64);
    loadV(0);
    asm volatile("s_waitcnt vmcnt(0)" ::: "memory");
    writeV(0);
    asm volatile("s_waitcnt lgkmcnt(0)" ::: "memory");
    __builtin_amdgcn_s_barrier();
    asm volatile("" ::: "memory");

    for (int jt = 0; jt < ntiles; ++jt) {
        const int curV = jt & 1;
        const int curK = jt % 3;
        const int kv0 = jt * 64;
        // issue order matters: V loads first, then K stage (FIFO: waiting on V regs
        // at writeV retires sK_{j+1} but leaves sK_{j+2} in flight across the barrier)
        if (jt + 1 < ntiles) loadV(kv0 + 64);
        if (jt + 2 < ntiles) stageK((jt + 2) % 3, kv0 + 128);

        const bool diag = (jt == qb);
        const int rsw = lr & 7;
        float p[4][4];
        __builtin_amdgcn_s_setprio(1);
        #pragma unroll
        for (int t = 0; t < 4; ++t) {
            f32x4 sacc = {0.f, 0.f, 0.f, 0.f};
            #pragma unroll
            for (int ks = 0; ks < 2; ++ks) {
                bf16x8 kf = *reinterpret_cast<const bf16x8*>(
                    &Ks[curK][(t * 16 + lr) * 64 + (((ks * 4 + lq) ^ rsw) * 8)]);
                sacc = mfma16(kf, qf[ks], sacc);   // S[k=t*16+lq*4+r][q=lr]
            }
            #pragma unroll
            for (int r = 0; r < 4; ++r) {
                float e = exp2f(sacc[r] * CLOG2E);
                if (diag && (t * 16 + lq * 4 + r > w * 16 + lr)) e = 0.f;
                p[t][r] = e;
                lsum += e;
            }
        }
        __builtin_amdgcn_s_setprio(0);

        // T12: pack P to bf16 and redistribute across lq groups via permlane swaps
        unsigned P0[4], P1[4];
        #pragma unroll
        for (int t = 0; t < 4; ++t) {
            asm("v_cvt_pk_bf16_f32 %0, %1, %2" : "=v"(P0[t]) : "v"(p[t][0]), "v"(p[t][1]));
            asm("v_cvt_pk_bf16_f32 %0, %1, %2" : "=v"(P1[t]) : "v"(p[t][2]), "v"(p[t][3]));
        }
        __builtin_amdgcn_s_setprio(1);
        #pragma unroll
        for (int ks = 0; ks < 2; ++ks) {
            unsigned a0 = P0[2 * ks], b0 = P0[2 * ks + 1];
            asm volatile("v_permlane32_swap_b32 %0, %1" : "+v"(a0), "+v"(b0));
            asm volatile("v_permlane16_swap_b32 %0, %1" : "+v"(a0), "+v"(b0));
            unsigned a1 = P1[2 * ks], b1 = P1[2 * ks + 1];
            asm volatile("v_permlane32_swap_b32 %0, %1" : "+v"(a1), "+v"(b1));
            asm volatile("v_permlane16_swap_b32 %0, %1" : "+v"(a1), "+v"(b1));
            union { unsigned u[4]; bf16x8 v8; } pk_;
            pk_.u[0] = a0; pk_.u[1] = a1; pk_.u[2] = b0; pk_.u[3] = b1;
            bf16x8 pa = pk_.v8;   // P[q=lr][kv = ks*32 + lq*8 + e]
            #pragma unroll
            for (int db = 0; db < 4; ++db) {
                int row = db * 16 + lr;
                bf16x8 vf = *reinterpret_cast<const bf16x8*>(
                    &Vt[curV][row][(ks * 32 + lq * 8) ^ (((row >> 3) & 7) << 3)]);
                o[db] = mfma16(pa, vf, o[db]);
            }
        }
        __builtin_amdgcn_s_setprio(0);

        if (jt + 1 < ntiles) writeV(curV ^ 1);  // implicit vmcnt wait on vv regs only
        asm volatile("s_waitcnt lgkmcnt(0)" ::: "memory");
        __builtin_amdgcn_s_barrier();           // NO vmcnt drain: sK_{j+2} stays in flight
        asm volatile("" ::: "memory");
    }

    // full row-sums: reduce across the 4 lq groups, then gather per output row
    lsum += __shfl_xor(lsum, 16);
    lsum += __shfl_xor(lsum, 32);
    float inv[4];
    #pragma unroll
    for (int r = 0; r < 4; ++r)
        inv[r] = 1.0f / __shfl(lsum, lq * 4 + r);

    #pragma unroll
    for (int db = 0; db < 4; ++db)
        #pragma unroll
        for (int r = 0; r < 4; ++r) {
            float v = o[db][r] * inv[r];
            att[(size_t)(b * 2048 + qr0 + lq * 4 + r) * 768 + h * 64 + db * 16 + lr] = (bf16)v;
        }
}

// ---------------- launch ----------------
extern "C" void kernel_launch(void* const* d_in, const int* in_sizes, int n_in,
                              void* d_out, int out_size, void* d_ws, size_t ws_size,
                              hipStream_t stream) {
    const float* x      = (const float*)d_in[0];
    const float* w_attn = (const float*)d_in[1];
    const float* b_attn = (const float*)d_in[2];
    const float* w_proj = (const float*)d_in[3];
    const float* b_proj = (const float*)d_in[4];

    char* ws = (char*)d_ws;
    bf16* xb  = (bf16*)(ws + 0);          // 4096x768   = 6291456 B
    bf16* wab = (bf16*)(ws + 6291456);    // 2304x768   = 3538944 B
    bf16* wpb = (bf16*)(ws + 9830400);    //  768x768   = 1179648 B
    bf16* qkv = (bf16*)(ws + 11010048);   // 4096x2304  = 18874368 B
    bf16* att = (bf16*)(ws + 29884416);   // 4096x768   = 6291456 B

    k_cast3<<<2048, 256, 0, stream>>>(x, w_attn, w_proj, xb, wab, wpb);

    dim3 g1(2304 / 128, 4096 / 128);
    k_gemm_bt<true><<<g1, 256, 0, stream>>>(xb, wab, b_attn, qkv, 4096, 2304, 768);

    k_flash_attn<<<768, 256, 0, stream>>>(qkv, att);

    dim3 g2(768 / 128, 4096 / 128);
    k_gemm_bt<false><<<g2, 256, 0, stream>>>(att, wpb, b_proj, d_out, 4096, 768, 768);
}

// Round 5
// 88.385 us; speedup vs baseline: 2.2760x; 1.1955x over previous
//
#include <hip/hip_runtime.h>
#include <hip/hip_bf16.h>
#include <stdint.h>

typedef __bf16 bf16;
typedef __bf16 bf16x4 __attribute__((ext_vector_type(4)));
typedef __bf16 bf16x8 __attribute__((ext_vector_type(8)));
typedef float f32x4 __attribute__((ext_vector_type(4)));

__device__ __forceinline__ f32x4 mfma16(bf16x8 a, bf16x8 b, f32x4 c) {
    return __builtin_amdgcn_mfma_f32_16x16x32_bf16(a, b, c, 0, 0, 0);
}

__device__ __forceinline__ void gload_lds16(const void* g, void* l) {
    __builtin_amdgcn_global_load_lds((__attribute__((address_space(1))) void*)g,
                                     (__attribute__((address_space(3))) void*)l,
                                     16, 0, 0);
}

// ---------------- fused cast fp32 -> bf16 for all three inputs ----------------
__global__ void k_cast3(const float* __restrict__ x, const float* __restrict__ wa,
                        const float* __restrict__ wp, bf16* __restrict__ xb,
                        bf16* __restrict__ wab, bf16* __restrict__ wpb) {
    const int N1 = 786432, N2 = 442368, N3 = 147456;  // float4 chunks
    int i = blockIdx.x * blockDim.x + threadIdx.x;
    int stride = gridDim.x * blockDim.x;
    for (; i < N1 + N2 + N3; i += stride) {
        const float* src; bf16* dst; int j = i;
        if (j < N1)           { src = x;  dst = xb; }
        else if (j < N1 + N2) { src = wa; dst = wab; j -= N1; }
        else                  { src = wp; dst = wpb; j -= N1 + N2; }
        float4 v = reinterpret_cast<const float4*>(src)[j];
        bf16x4 o = { (bf16)v.x, (bf16)v.y, (bf16)v.z, (bf16)v.w };
        reinterpret_cast<bf16x4*>(dst)[j] = o;
    }
}

// ---------------- GEMM: C[M,N] = A[M,K] * W[N,K]^T + bias ----------------
// 128x128 tile, BK=64, XOR-swizzled LDS (both-sides: pre-swizzled gload src +
// swizzled ds_read) so the 128B row stride is conflict-free (2-way only).
template<bool BF16_OUT>
__global__ __launch_bounds__(256) void k_gemm_bt(
        const bf16* __restrict__ A, const bf16* __restrict__ W,
        const float* __restrict__ bias, void* __restrict__ Cout,
        int M, int N, int K) {
    __shared__ bf16 As[128 * 64];
    __shared__ bf16 Ws[128 * 64];
    const int tid = threadIdx.x;
    const int l = tid & 63, w = tid >> 6;
    const int lr = l & 15, lq = l >> 4;
    const int wm = w >> 1, wn = w & 1;
    const int bm = blockIdx.y * 128, bn = blockIdx.x * 128;

    f32x4 acc[4][4] = {};

    for (int k0 = 0; k0 < K; k0 += 64) {
        __syncthreads();
        #pragma unroll
        for (int i = 0; i < 4; ++i) {
            int c = tid + i * 256;              // 0..1023 chunks of 16B
            int row = c >> 3, j = c & 7;        // 128 rows x 8 chunks
            int src8 = (j ^ (row & 7)) * 8;
            gload_lds16(A + (size_t)(bm + row) * K + k0 + src8, As + c * 8);
            gload_lds16(W + (size_t)(bn + row) * K + k0 + src8, Ws + c * 8);
        }
        __syncthreads();
        bf16x8 af[2][4], wf[2][4];
        #pragma unroll
        for (int ks = 0; ks < 2; ++ks)
            #pragma unroll
            for (int f = 0; f < 4; ++f) {
                int ra = wm * 64 + f * 16 + lr;
                int rb = wn * 64 + f * 16 + lr;
                af[ks][f] = *reinterpret_cast<const bf16x8*>(
                    As + ra * 64 + (((ks * 4 + lq) ^ (lr & 7)) * 8));
                wf[ks][f] = *reinterpret_cast<const bf16x8*>(
                    Ws + rb * 64 + (((ks * 4 + lq) ^ (lr & 7)) * 8));
            }
        #pragma unroll
        for (int ks = 0; ks < 2; ++ks)
            #pragma unroll
            for (int fm = 0; fm < 4; ++fm)
                #pragma unroll
                for (int fn = 0; fn < 4; ++fn)
                    acc[fm][fn] = mfma16(af[ks][fm], wf[ks][fn], acc[fm][fn]);
    }

    #pragma unroll
    for (int fm = 0; fm < 4; ++fm) {
        #pragma unroll
        for (int fn = 0; fn < 4; ++fn) {
            int row = bm + wm * 64 + fm * 16 + lq * 4;
            int col = bn + wn * 64 + fn * 16 + lr;
            float bv = bias[col];
            #pragma unroll
            for (int r = 0; r < 4; ++r) {
                float v = acc[fm][fn][r] + bv;
                if (BF16_OUT)
                    ((bf16*)Cout)[(size_t)(row + r) * N + col] = (bf16)v;
                else
                    ((float*)Cout)[(size_t)(row + r) * N + col] = v;
            }
        }
    }
}

// ---------------- causal flash attention ----------------
// mode 1: split-KV, 1152 CTAs, chunks of <=16 tiles, partials to ws.
// mode 0: fallback, 768 CTAs, balanced qb map (R4 behavior).
#define CLOG2E 1.02014439f   // (1/sqrt(2)) * log2(e)

__global__ __launch_bounds__(256, 3) void k_flash_attn(
        const bf16* __restrict__ qkv, bf16* __restrict__ att,
        float* __restrict__ part, int mode) {
    __shared__ bf16 Ks[3][4096];      // [kv][d], chunk j of row holds src chunk j^(row&7)
    __shared__ bf16 Vt[2][64][72];    // [d][kv], kv XOR-swizzled by ((d>>3)&7)<<3

    const int tid = threadIdx.x;
    const int l = tid & 63, w = tid >> 6;
    const int lr = l & 15, lq = l >> 4;

    const int bid = blockIdx.x;
    int qb, h, b, jt0, jt1, slot;
    bool dopart;
    if (mode) {
        int bh = bid % 24, idx = bid / 24;
        h = bh % 12; b = bh / 12;
        if (idx < 16)      { qb = 16 + idx;  jt0 = 0;  jt1 = 16;     dopart = true;  slot = (bh * 16 + idx) * 2; }
        else if (idx < 32) { qb = 47 - idx;  jt0 = 16; jt1 = qb + 1; dopart = true;  slot = (bh * 16 + (qb - 16)) * 2 + 1; }
        else               { qb = 47 - idx;  jt0 = 0;  jt1 = qb + 1; dopart = false; slot = 0; }
    } else {
        const int s = bid >> 8, i = (bid >> 3) & 31, t7 = bid & 7;
        if (s == 0)      qb = i;
        else if (s == 2) qb = (i + 16) & 31;
        else             qb = (i < 8) ? (31 - 2 * i) : (i < 16) ? (30 - 2 * i)
                           : (i < 24) ? (62 - 2 * i) : (63 - 2 * i);
        const int hb = s * 8 + t7;
        h = hb % 12; b = hb / 12;
        jt0 = 0; jt1 = qb + 1; dopart = false; slot = 0;
    }

    const bf16* Qp = qkv + (size_t)b * 2048 * 2304 + h * 64;
    const bf16* Kp = Qp + 768;
    const bf16* Vp = Qp + 1536;

    const int qr0 = qb * 64 + w * 16;

    bf16x8 qf[2];
    #pragma unroll
    for (int ks = 0; ks < 2; ++ks)
        qf[ks] = *reinterpret_cast<const bf16x8*>(
            Qp + (size_t)(qr0 + lr) * 2304 + ks * 32 + lq * 8);

    f32x4 o[4] = {};
    float lsum = 0.f;

    auto stageK = [&](int buf, int kv0) {
        #pragma unroll
        for (int ii = 0; ii < 2; ++ii) {
            int c = tid + ii * 256;
            int row = c >> 3, j = c & 7;
            gload_lds16(Kp + (size_t)(kv0 + row) * 2304 + ((j ^ (row & 7)) * 8),
                        &Ks[buf][c * 8]);
        }
    };
    bf16x8 vv0, vv1;
    auto loadV = [&](int kv0) {
        vv0 = *reinterpret_cast<const bf16x8*>(
            Vp + (size_t)(kv0 + (tid >> 3)) * 2304 + (tid & 7) * 8);
        vv1 = *reinterpret_cast<const bf16x8*>(
            Vp + (size_t)(kv0 + 32 + (tid >> 3)) * 2304 + (tid & 7) * 8);
    };
    auto writeV = [&](int buf) {
        int kv = tid >> 3, d0 = (tid & 7) * 8;
        int sw = (tid & 7) << 3;
        #pragma unroll
        for (int j = 0; j < 8; ++j) {
            int d = d0 + j;
            Vt[buf][d][kv ^ sw]        = vv0[j];
            Vt[buf][d][(kv + 32) ^ sw] = vv1[j];
        }
    };

    // prologue
    stageK(0, jt0 * 64);
    if (jt1 > jt0 + 1) stageK(1, (jt0 + 1) * 64);
    loadV(jt0 * 64);
    asm volatile("s_waitcnt vmcnt(0)" ::: "memory");
    writeV(0);
    asm volatile("s_waitcnt lgkmcnt(0)" ::: "memory");
    __builtin_amdgcn_s_barrier();
    asm volatile("" ::: "memory");

    for (int jt = jt0; jt < jt1; ++jt) {
        const int curV = (jt - jt0) & 1;
        const int curK = (jt - jt0) % 3;
        const int kv0 = jt * 64;
        if (jt + 1 < jt1) loadV(kv0 + 64);
        if (jt + 2 < jt1) stageK((jt + 2 - jt0) % 3, kv0 + 128);

        const bool diag = (jt == qb);
        const int rsw = lr & 7;
        float p[4][4];
        __builtin_amdgcn_s_setprio(1);
        #pragma unroll
        for (int t = 0; t < 4; ++t) {
            f32x4 sacc = {0.f, 0.f, 0.f, 0.f};
            #pragma unroll
            for (int ks = 0; ks < 2; ++ks) {
                bf16x8 kf = *reinterpret_cast<const bf16x8*>(
                    &Ks[curK][(t * 16 + lr) * 64 + (((ks * 4 + lq) ^ rsw) * 8)]);
                sacc = mfma16(kf, qf[ks], sacc);   // S[k=t*16+lq*4+r][q=lr]
            }
            #pragma unroll
            for (int r = 0; r < 4; ++r) {
                float e = __builtin_amdgcn_exp2f(sacc[r] * CLOG2E);
                if (diag && (t * 16 + lq * 4 + r > w * 16 + lr)) e = 0.f;
                p[t][r] = e;
                lsum += e;
            }
        }
        __builtin_amdgcn_s_setprio(0);

        // T12: pack P to bf16 and redistribute across lq groups via permlane swaps
        unsigned P0[4], P1[4];
        #pragma unroll
        for (int t = 0; t < 4; ++t) {
            asm("v_cvt_pk_bf16_f32 %0, %1, %2" : "=v"(P0[t]) : "v"(p[t][0]), "v"(p[t][1]));
            asm("v_cvt_pk_bf16_f32 %0, %1, %2" : "=v"(P1[t]) : "v"(p[t][2]), "v"(p[t][3]));
        }
        __builtin_amdgcn_s_setprio(1);
        #pragma unroll
        for (int ks = 0; ks < 2; ++ks) {
            unsigned a0 = P0[2 * ks], b0 = P0[2 * ks + 1];
            asm volatile("v_permlane32_swap_b32 %0, %1" : "+v"(a0), "+v"(b0));
            asm volatile("v_permlane16_swap_b32 %0, %1" : "+v"(a0), "+v"(b0));
            unsigned a1 = P1[2 * ks], b1 = P1[2 * ks + 1];
            asm volatile("v_permlane32_swap_b32 %0, %1" : "+v"(a1), "+v"(b1));
            asm volatile("v_permlane16_swap_b32 %0, %1" : "+v"(a1), "+v"(b1));
            union { unsigned u[4]; bf16x8 v8; } pk_;
            pk_.u[0] = a0; pk_.u[1] = a1; pk_.u[2] = b0; pk_.u[3] = b1;
            bf16x8 pa = pk_.v8;   // P[q=lr][kv = ks*32 + lq*8 + e]
            #pragma unroll
            for (int db = 0; db < 4; ++db) {
                int row = db * 16 + lr;
                bf16x8 vf = *reinterpret_cast<const bf16x8*>(
                    &Vt[curV][row][(ks * 32 + lq * 8) ^ (((row >> 3) & 7) << 3)]);
                o[db] = mfma16(pa, vf, o[db]);
            }
        }
        __builtin_amdgcn_s_setprio(0);

        if (jt + 1 < jt1) writeV(curV ^ 1);  // implicit vmcnt wait on vv regs only
        asm volatile("s_waitcnt lgkmcnt(0)" ::: "memory");
        __builtin_amdgcn_s_barrier();        // no vmcnt drain: deep K stage stays in flight
        asm volatile("" ::: "memory");
    }

    // row sums across the 4 lq groups (lane holds full sum for row q=lr after this)
    lsum += __shfl_xor(lsum, 16);
    lsum += __shfl_xor(lsum, 32);

    if (dopart) {
        float* pb = part + (size_t)slot * 4160;
        #pragma unroll
        for (int db = 0; db < 4; ++db)
            #pragma unroll
            for (int r = 0; r < 4; ++r)
                pb[(w * 16 + lq * 4 + r) * 64 + db * 16 + lr] = o[db][r];
        if (lq == 0) pb[4096 + w * 16 + lr] = lsum;
    } else {
        float inv[4];
        #pragma unroll
        for (int r = 0; r < 4; ++r)
            inv[r] = 1.0f / __shfl(lsum, lq * 4 + r);
        #pragma unroll
        for (int db = 0; db < 4; ++db)
            #pragma unroll
            for (int r = 0; r < 4; ++r) {
                float v = o[db][r] * inv[r];
                att[(size_t)(b * 2048 + qr0 + lq * 4 + r) * 768 + h * 64 + db * 16 + lr] = (bf16)v;
            }
    }
}

// ---------------- combine split-KV partials ----------------
__global__ __launch_bounds__(256) void k_attn_reduce(
        const float* __restrict__ part, bf16* __restrict__ att) {
    int g = blockIdx.x;                 // 384 = 24 bh * 16 qb
    int bh = g / 16, q16 = g % 16, qb = 16 + q16;
    int h = bh % 12, b = bh / 12;
    const float* p0 = part + (size_t)((bh * 16 + q16) * 2) * 4160;
    const float* p1 = p0 + 4160;
    for (int e = threadIdx.x; e < 4096; e += 256) {
        int row = e >> 6, col = e & 63;
        float O = p0[e] + p1[e];
        float L = p0[4096 + row] + p1[4096 + row];
        att[(size_t)(b * 2048 + qb * 64 + row) * 768 + h * 64 + col] = (bf16)(O / L);
    }
}

// ---------------- launch ----------------
extern "C" void kernel_launch(void* const* d_in, const int* in_sizes, int n_in,
                              void* d_out, int out_size, void* d_ws, size_t ws_size,
                              hipStream_t stream) {
    const float* x      = (const float*)d_in[0];
    const float* w_attn = (const float*)d_in[1];
    const float* b_attn = (const float*)d_in[2];
    const float* w_proj = (const float*)d_in[3];
    const float* b_proj = (const float*)d_in[4];

    char* ws = (char*)d_ws;
    bf16* xb   = (bf16*)(ws + 0);          // 4096x768   = 6291456 B
    bf16* wab  = (bf16*)(ws + 6291456);    // 2304x768   = 3538944 B
    bf16* wpb  = (bf16*)(ws + 9830400);    //  768x768   = 1179648 B
    bf16* qkv  = (bf16*)(ws + 11010048);   // 4096x2304  = 18874368 B
    bf16* att  = (bf16*)(ws + 29884416);   // 4096x768   = 6291456 B
    float* part = (float*)(ws + 36175872); // 768 slots x 4160 f32 = 12779520 B
    const unsigned long long WS_NEEDED = 36175872ull + 12779520ull;

    k_cast3<<<2048, 256, 0, stream>>>(x, w_attn, w_proj, xb, wab, wpb);

    dim3 g1(2304 / 128, 4096 / 128);
    k_gemm_bt<true><<<g1, 256, 0, stream>>>(xb, wab, b_attn, qkv, 4096, 2304, 768);

    if (ws_size >= WS_NEEDED) {
        k_flash_attn<<<1152, 256, 0, stream>>>(qkv, att, part, 1);
        k_attn_reduce<<<384, 256, 0, stream>>>(part, att);
    } else {
        k_flash_attn<<<768, 256, 0, stream>>>(qkv, att, part, 0);
    }

    dim3 g2(768 / 128, 4096 / 128);
    k_gemm_bt<false><<<g2, 256, 0, stream>>>(att, wpb, b_proj, d_out, 4096, 768, 768);
}